// Round 3
// baseline (20.812 us; speedup 1.0000x reference)
//
#include <hip/hip_runtime.h>

// Problem geometry (fixed by reference):
//   preds : (B=2, T=8, E=16, H=128, W=256) f32, idx ((b*8+t)*16+e)*HW + hw
//   target: (B=2, T=8, 1,    H=128, W=256) f32
//   output: scalar f32
#define HW    32768   // 128*256
#define T_DIM 8
#define E_DIM 16
#define NPOS  65536   // B * HW
#define BLK   256
#define NBLK  1024    // 2 b * 512 hw-groups of 64

__device__ __forceinline__ float block_reduce_256(float v, float* lds) {
#pragma unroll
    for (int off = 32; off; off >>= 1)
        v += __shfl_down(v, off, 64);
    int lane = threadIdx.x & 63;
    int wid  = threadIdx.x >> 6;
    if (lane == 0) lds[wid] = v;
    __syncthreads();
    return lds[0] + lds[1] + lds[2] + lds[3];
}

// term1/16 - term2core/256 for one (b,t,hw): p[16] vs tgt
__device__ __forceinline__ float crps_term(const float* p, float tgt) {
    float t1 = 0.f;
#pragma unroll
    for (int e = 0; e < E_DIM; ++e)
        t1 += fabsf(p[e] - tgt);
    float s = 0.f;
#pragma unroll
    for (int i = 0; i < E_DIM; ++i)
#pragma unroll
        for (int j = i + 1; j < E_DIM; ++j)
            s += fabsf(p[i] - p[j]);
    return t1 * (1.f / 16.f) - s * (1.f / 256.f);
}

// Block = 4 waves x 64 lanes. Wave w owns t in {2w, 2w+1} for 64 consecutive
// hw positions. Every preds element is loaded from global exactly once;
// pair-boundary temporal diffs (t=2w+1 -> 2w+2) go through LDS.
__global__ __launch_bounds__(BLK) void crps_partial(const float* __restrict__ preds,
                                                    const float* __restrict__ target,
                                                    float* __restrict__ partials) {
    const int lane = threadIdx.x & 63;
    const int w    = threadIdx.x >> 6;       // wave 0..3 -> t-pair
    const int grp  = blockIdx.x & 511;       // hw group of 64
    const int b    = blockIdx.x >> 9;        // 0..1
    const int hw   = grp * 64 + lane;
    const int t0   = 2 * w;

    const float* pb = preds  + hw;
    const float* tb = target + hw;

    float cur0[E_DIM], cur1[E_DIM];
#pragma unroll
    for (int e = 0; e < E_DIM; ++e)
        cur0[e] = pb[((size_t)((b * T_DIM + t0) * E_DIM) + e) * HW];
#pragma unroll
    for (int e = 0; e < E_DIM; ++e)
        cur1[e] = pb[((size_t)((b * T_DIM + t0 + 1) * E_DIM) + e) * HW];
    const float tgt0 = tb[(size_t)(b * T_DIM + t0) * HW];
    const float tgt1 = tb[(size_t)(b * T_DIM + t0 + 1) * HW];

    // publish cur1 (t = 2w+1) for the next wave's boundary transition
    __shared__ float xch[3][E_DIM][64];      // 12 KB
    if (w < 3) {
#pragma unroll
        for (int e = 0; e < E_DIM; ++e)
            xch[w][e][lane] = cur1[e];       // stride-1 per lane: conflict-free
    }

    // heavy compute overlaps with other waves' loads/LDS writes
    float acc = crps_term(cur0, tgt0) + crps_term(cur1, tgt1);
    float tacc = 0.f;
#pragma unroll
    for (int e = 0; e < E_DIM; ++e)
        tacc += fabsf(cur1[e] - cur0[e]);    // within-pair transition

    __syncthreads();

    if (w > 0) {                             // boundary transition 2w-1 -> 2w
#pragma unroll
        for (int e = 0; e < E_DIM; ++e)
            tacc += fabsf(cur0[e] - xch[w - 1][e][lane]);
    }

    float v = acc * (1.f / 8.f) + tacc * (0.1f / 112.f);

    __shared__ float rlds[4];
    float bsum = block_reduce_256(v, rlds);
    if (threadIdx.x == 0)
        partials[blockIdx.x] = bsum;
}

__global__ __launch_bounds__(BLK) void crps_final(const float* __restrict__ partials,
                                                  float* __restrict__ out) {
    float v = 0.f;
#pragma unroll
    for (int i = 0; i < NBLK / BLK; ++i)     // 4 partials per thread
        v += partials[i * BLK + threadIdx.x];
    __shared__ float lds[4];
    float total = block_reduce_256(v, lds);
    if (threadIdx.x == 0)
        out[0] = total * (1.f / (float)NPOS);
}

extern "C" void kernel_launch(void* const* d_in, const int* in_sizes, int n_in,
                              void* d_out, int out_size, void* d_ws, size_t ws_size,
                              hipStream_t stream) {
    const float* preds  = (const float*)d_in[0];
    const float* target = (const float*)d_in[1];
    float* out      = (float*)d_out;
    float* partials = (float*)d_ws;   // 1024 floats = 4 KB scratch

    crps_partial<<<NBLK, BLK, 0, stream>>>(preds, target, partials);
    crps_final<<<1, BLK, 0, stream>>>(partials, out);
}

// Round 4
// 13.478 us; speedup vs baseline: 1.5441x; 1.5441x over previous
//
#include <hip/hip_runtime.h>

// Problem geometry (fixed by reference):
//   preds : (B=2, T=8, E=16, H=128, W=256) f32, idx ((b*8+t)*16+e)*HW + hw
//   target: (B=2, T=8, 1,    H=128, W=256) f32
//   output: scalar f32
#define HW    32768   // 128*256
#define T_DIM 8
#define E_DIM 16
#define NPOS  65536   // B * HW
#define BLK   256
#define NTHREADS 262144                 // B * HW * 4 t-pairs
#define NBLK  (NTHREADS / BLK)          // 1024

__device__ __forceinline__ float block_reduce_256(float v, float* lds) {
#pragma unroll
    for (int off = 32; off; off >>= 1)
        v += __shfl_down(v, off, 64);
    int lane = threadIdx.x & 63;
    int wid  = threadIdx.x >> 6;
    if (lane == 0) lds[wid] = v;
    __syncthreads();
    return lds[0] + lds[1] + lds[2] + lds[3];
}

// term1/16 - term2core/256 for one (b,t,hw): p[16] vs tgt
__device__ __forceinline__ float crps_term(const float* p, float tgt) {
    float t1 = 0.f;
#pragma unroll
    for (int e = 0; e < E_DIM; ++e)
        t1 += fabsf(p[e] - tgt);
    float s = 0.f;
#pragma unroll
    for (int i = 0; i < E_DIM; ++i)
#pragma unroll
        for (int j = i + 1; j < E_DIM; ++j)
            s += fabsf(p[i] - p[j]);
    return t1 * (1.f / 16.f) - s * (1.f / 256.f);
}

// Thread (b, hw, k) owns t in {2k, 2k+1}. Lane layout: lane = (hw%16)*4 + k,
// so the thread holding the t=2k-1 values (pair k-1, same hw) is lane-1.
// Pair-boundary temporal diffs come via __shfl — no barrier, no LDS, no
// redundant global loads. Every preds/target element is loaded exactly once.
__global__ __launch_bounds__(BLK) void crps_partial(const float* __restrict__ preds,
                                                    const float* __restrict__ target,
                                                    float* __restrict__ partials) {
    const int n  = blockIdx.x * BLK + threadIdx.x;   // 18 bits
    const int k  = n & 3;                            // t-pair 0..3 (lane bits)
    const int hw = (n >> 2) & (HW - 1);              // 15 bits
    const int b  = n >> 17;                          // 0..1
    const int t0 = 2 * k;

    const float* pb = preds  + hw;
    const float* tb = target + hw;

    float cur0[E_DIM], cur1[E_DIM];
#pragma unroll
    for (int e = 0; e < E_DIM; ++e)
        cur0[e] = pb[((size_t)((b * T_DIM + t0) * E_DIM) + e) * HW];
#pragma unroll
    for (int e = 0; e < E_DIM; ++e)
        cur1[e] = pb[((size_t)((b * T_DIM + t0 + 1) * E_DIM) + e) * HW];
    const float tgt0 = tb[(size_t)(b * T_DIM + t0) * HW];
    const float tgt1 = tb[(size_t)(b * T_DIM + t0 + 1) * HW];

    // boundary transition t=2k-1 -> 2k: pull neighbor lane's cur1
    const int lane = threadIdx.x & 63;
    const int src  = (lane > 0) ? (lane - 1) : 0;
    float tacc = 0.f;
#pragma unroll
    for (int e = 0; e < E_DIM; ++e) {
        float pv = __shfl(cur1[e], src, 64);         // exec-sync, DS pipe
        if (k > 0)
            tacc += fabsf(cur0[e] - pv);
    }
    // within-pair transition t=2k -> 2k+1
#pragma unroll
    for (int e = 0; e < E_DIM; ++e)
        tacc += fabsf(cur1[e] - cur0[e]);

    float acc = crps_term(cur0, tgt0) + crps_term(cur1, tgt1);

    // per-(b,hw) scaling: crps terms averaged over 8 t; temporal over 112
    float v = acc * (1.f / 8.f) + tacc * (0.1f / 112.f);

    __shared__ float lds[4];
    float bsum = block_reduce_256(v, lds);
    if (threadIdx.x == 0)
        partials[blockIdx.x] = bsum;
}

__global__ __launch_bounds__(BLK) void crps_final(const float* __restrict__ partials,
                                                  float* __restrict__ out) {
    float v = 0.f;
#pragma unroll
    for (int i = 0; i < NBLK / BLK; ++i)            // 4 partials per thread
        v += partials[i * BLK + threadIdx.x];
    __shared__ float lds[4];
    float total = block_reduce_256(v, lds);
    if (threadIdx.x == 0)
        out[0] = total * (1.f / (float)NPOS);
}

extern "C" void kernel_launch(void* const* d_in, const int* in_sizes, int n_in,
                              void* d_out, int out_size, void* d_ws, size_t ws_size,
                              hipStream_t stream) {
    const float* preds  = (const float*)d_in[0];
    const float* target = (const float*)d_in[1];
    float* out      = (float*)d_out;
    float* partials = (float*)d_ws;   // 1024 floats = 4 KB scratch

    crps_partial<<<NBLK, BLK, 0, stream>>>(preds, target, partials);
    crps_final<<<1, BLK, 0, stream>>>(partials, out);
}